// Round 11
// baseline (113.108 us; speedup 1.0000x reference)
//
#include <hip/hip_runtime.h>
#include <hip/hip_bf16.h>

#define HEADS 12
#define HD 64
#define PADW 32
#define EMBED 768
#define LSEQ 2048
#define QKV_N (3 * HEADS * HD)   // 2304
#define LPAD (LSEQ + 64)         // 2112

typedef short short8 __attribute__((ext_vector_type(8)));
typedef short short4v __attribute__((ext_vector_type(4)));
typedef float f32x4 __attribute__((ext_vector_type(4)));

// Static scratch, fully overwritten every call (poison-safe).
__device__ short g_xb[LSEQ * EMBED];        // x bf16             [2048][768]
__device__ short g_wqkvT[QKV_N * EMBED];    // w_qkv^T bf16       [2304][768]
__device__ short g_woutT[EMBED * EMBED];    // w_out^T bf16       [768][768]
__device__ short g_qkvb[LSEQ * QKV_N];      // qkv bf16           [2048][2304]
__device__ short g_vT[HEADS * HD * LPAD];   // V^T bf16, 0-padded [768][2112]
__device__ short g_attnb[LSEQ * EMBED];     // attn out bf16      [2048][768]

__device__ __forceinline__ short f2bf(float f) {
  unsigned x = __builtin_bit_cast(unsigned, f);
  x += 0x7fffu + ((x >> 16) & 1u);   // RNE
  return (short)(x >> 16);
}

#define GLB(p) ((const __attribute__((address_space(1))) void*)(p))
#define LDS(p) ((__attribute__((address_space(3))) void*)(p))

// ---------------------------------------------------------------------------
// prep (unchanged, verified): A = cast x, B = w_qkv transpose, C = w_out
// transpose, D = zero vT pads. One dispatch, 3864 blocks.
// ---------------------------------------------------------------------------
#define PREP_A 1536              // (2048*768/4)/256
#define PREP_B 1728              // w_qkv: 72 x 24 tiles of 32x32
#define PREP_C 576               // w_out: 24 x 24
#define PREP_D 24                // vT pad zero
#define PREP_TOT (PREP_A + PREP_B + PREP_C + PREP_D)

__global__ __launch_bounds__(256) void prep(
    const float* __restrict__ x, const float* __restrict__ w_qkv,
    const float* __restrict__ w_out, short* __restrict__ xb,
    short* __restrict__ wqkvT, short* __restrict__ woutT,
    short* __restrict__ vT) {
  __shared__ float T[32][33];
  const int b = blockIdx.x, tid = threadIdx.x;
  if (b < PREP_A) {
    int i = b * 256 + tid;
    float4 v = ((const float4*)x)[i];
    short4v o;
    o[0] = f2bf(v.x); o[1] = f2bf(v.y); o[2] = f2bf(v.z); o[3] = f2bf(v.w);
    ((short4v*)xb)[i] = o;
  } else if (b < PREP_A + PREP_B + PREP_C) {
    const float* W; short* WT; int N, bx, by;
    if (b < PREP_A + PREP_B) {
      int t = b - PREP_A; W = w_qkv; WT = wqkvT; N = QKV_N; bx = t % 72; by = t / 72;
    } else {
      int t = b - PREP_A - PREP_B; W = w_out; WT = woutT; N = EMBED; bx = t % 24; by = t / 24;
    }
    const int K = EMBED;
    int tx = tid & 31, ty = tid >> 5;
    int n0 = bx * 32, k0 = by * 32;
#pragma unroll
    for (int p = 0; p < 4; ++p)
      T[ty + p * 8][tx] = W[(size_t)(k0 + ty + p * 8) * N + n0 + tx];
    __syncthreads();
#pragma unroll
    for (int p = 0; p < 4; ++p)
      WT[(size_t)(n0 + ty + p * 8) * K + k0 + tx] = f2bf(T[tx][ty + p * 8]);
  } else {
    int j = (b - PREP_A - PREP_B - PREP_C) * 256 + tid;
    int hd = j >> 3, side = (j >> 2) & 1, off = (j & 3) * 8;
    short8 z = {};
    *(short8*)&vT[(size_t)hd * LPAD + side * 2080 + off] = z;
  }
}

// ---------------------------------------------------------------------------
// ROUND 11 (resubmit — broker timeout): r9 verified structure (64x64xBK64,
// XOR-swizzled staging) with two step-latency attacks. r9 calibration:
// removing 24 K-steps saved 4.6us -> T_step ~ 450cy ~ HBM latency(900cy)/
// depth(2). So:
//  (a) prefetch depth 2 -> 3: 4 LDS buffers (64KiB, 2 blocks/CU; r8 proved
//      occupancy-neutral). vmcnt ledger: prologue stages {0,1,2}=12 loads;
//      iter j waits vmcnt(8) (retires stage j), stages j+3 into (j+3)&3
//      (overwrites buf read at j-1 -> WAR-safe past this iter's barrier);
//      peeled tail vmcnt(4), vmcnt(0).
//  (b) XCD-aware bid swizzle (bijective, nwg%8==0 for 1152 and 384):
//      swz=(bid&7)*(nwg/8)+(bid>>3). Each XCD owns a contiguous by-band;
//      its B-panel (3.5MB gemm1 / 1.1MB gemm2) fits the 4MiB per-XCD L2
//      -> B loads become L2 hits (~200cy) instead of HBM (~900cy).
// ---------------------------------------------------------------------------
template <bool OUT_BF16, bool FUSE_VT>
__global__ __launch_bounds__(256) void gemm_pipe64(
    const short* __restrict__ A, const short* __restrict__ Bt,
    const float* __restrict__ bias, void* __restrict__ Cv,
    short* __restrict__ vT, int M, int N, int K) {
  constexpr int BUF = 2 * 64 * 64;               // shorts: A(4096)+B(4096)
  __shared__ __align__(16) short lds_s[4 * BUF]; // 65536 B; epilogue reuses

  const int tid = threadIdx.x;
  // XCD-chunked block swizzle (gridDim.x % 8 == 0 for both call sites).
  const int cpx = gridDim.x >> 3;
  const int swz = (blockIdx.x & 7) * cpx + (blockIdx.x >> 3);
  const int gw = N >> 6;                         // tiles along N
  const int bx = swz % gw, by = swz / gw;

  const int wv = tid >> 6, lane = tid & 63;
  const int wm = wv >> 1, wn = wv & 1;
  const int lanelo = lane & 15, quad = lane >> 4;
  const int m0 = by * 64, n0 = bx * 64;
  const int srow8 = lane >> 3, schk = lane & 7;  // 8 rows x 8 16B chunks
  const int sgc = schk ^ srow8;                  // swizzled global chunk
  const int xk = lanelo & 7;                     // read-side XOR key

  f32x4 acc[2][2] = {};

  auto stage = [&](int j, int buf) {
    short* Ab = lds_s + buf * BUF;
    short* Bb = Ab + 64 * 64;
    const int k0 = j * 64;
#pragma unroll
    for (int c = 0; c < 2; ++c) {                // 8 rows per pass, 2 passes
      int row = wv * 16 + c * 8 + srow8;         // (row&7)==srow8
      const short* ga = A + (size_t)(m0 + row) * K + k0 + sgc * 8;
      __builtin_amdgcn_global_load_lds(GLB(ga), LDS(&Ab[(wv * 16 + c * 8) * 64]), 16, 0, 0);
    }
#pragma unroll
    for (int c = 0; c < 2; ++c) {
      int row = wv * 16 + c * 8 + srow8;
      const short* gb = Bt + (size_t)(n0 + row) * K + k0 + sgc * 8;
      __builtin_amdgcn_global_load_lds(GLB(gb), LDS(&Bb[(wv * 16 + c * 8) * 64]), 16, 0, 0);
    }
  };

  auto compute = [&](int buf) {
    short* Ab = lds_s + buf * BUF;
    short* Bb = Ab + 64 * 64;
    short8 af[2][2], bfr[2][2];                  // [ks][mt/nt]
#pragma unroll
    for (int ks = 0; ks < 2; ++ks) {
#pragma unroll
      for (int mt = 0; mt < 2; ++mt) {
        int row = wm * 32 + mt * 16 + lanelo;
        int p = (ks * 4 + quad) ^ xk;            // physical chunk
        af[ks][mt] = *(const short8*)&Ab[row * 64 + p * 8];
      }
#pragma unroll
      for (int nt = 0; nt < 2; ++nt) {
        int row = wn * 32 + nt * 16 + lanelo;
        int p = (ks * 4 + quad) ^ xk;
        bfr[ks][nt] = *(const short8*)&Bb[row * 64 + p * 8];
      }
    }
    asm volatile("s_waitcnt lgkmcnt(0)" ::: "memory");   // frags in regs
#pragma unroll
    for (int ks = 0; ks < 2; ++ks)
#pragma unroll
      for (int mt = 0; mt < 2; ++mt)
#pragma unroll
        for (int nt = 0; nt < 2; ++nt)
          acc[mt][nt] = __builtin_amdgcn_mfma_f32_16x16x32_bf16(
              af[ks][mt], bfr[ks][nt], acc[mt][nt], 0, 0, 0);
  };

  const int steps = K / 64;                      // 12
  stage(0, 0);
  stage(1, 1);
  stage(2, 2);
  for (int j = 0; j < steps - 2; ++j) {
    asm volatile("s_waitcnt vmcnt(8)" ::: "memory");  // stage j landed
    asm volatile("s_barrier" ::: "memory");
    if (j + 3 < steps) stage(j + 3, (j + 3) & 3);     // overwrites buf (j-1)&3
    compute(j & 3);
  }
  asm volatile("s_waitcnt vmcnt(4)" ::: "memory");
  asm volatile("s_barrier" ::: "memory");
  compute((steps - 2) & 3);
  asm volatile("s_waitcnt vmcnt(0)" ::: "memory");
  asm volatile("s_barrier" ::: "memory");
  compute((steps - 1) & 3);

  // ---- fused V^T scatter: any 16-col group with c0 % 192 >= 128 is V ----
  if (FUSE_VT) {
#pragma unroll
    for (int nt = 0; nt < 2; ++nt) {
      int c0 = n0 + wn * 32 + nt * 16;           // wave-uniform
      if ((c0 % 192) >= 128) {
        int h = c0 / 192, d0 = (c0 % 192) - 128;
#pragma unroll
        for (int mt = 0; mt < 2; ++mt) {
          int d = d0 + lanelo;
          int row0 = m0 + wm * 32 + mt * 16 + quad * 4;
          short4v o;
#pragma unroll
          for (int r = 0; r < 4; ++r) o[r] = f2bf(acc[mt][nt][r]);
          *(short4v*)&vT[(size_t)(h * 64 + d) * LPAD + PADW + row0] = o;
        }
      }
    }
  }

  // ---- coalesced epilogue through LDS (verified 64x64 paths) ----
  __syncthreads();                               // staging buffers dead
  if (OUT_BF16) {
    constexpr int ST = 80;
#pragma unroll
    for (int mt = 0; mt < 2; ++mt)
#pragma unroll
      for (int nt = 0; nt < 2; ++nt) {
        int rloc = wm * 32 + mt * 16 + quad * 4;
        int cloc = wn * 32 + nt * 16 + lanelo;
#pragma unroll
        for (int r = 0; r < 4; ++r)
          lds_s[(rloc + r) * ST + cloc] = f2bf(acc[mt][nt][r]);
      }
    __syncthreads();
    short* Cc = (short*)Cv;
#pragma unroll
    for (int rp = 0; rp < 64; rp += 32) {
      int row = rp + tid / 8, seg = tid % 8;
      short8 vv = *(const short8*)&lds_s[row * ST + seg * 8];
      *(short8*)&Cc[(size_t)(m0 + row) * N + n0 + seg * 8] = vv;
    }
  } else {
    constexpr int ST = 72;
    float* fl = (float*)lds_s;
#pragma unroll
    for (int mt = 0; mt < 2; ++mt)
#pragma unroll
      for (int nt = 0; nt < 2; ++nt) {
        int rloc = wm * 32 + mt * 16 + quad * 4;
        int cloc = wn * 32 + nt * 16 + lanelo;
#pragma unroll
        for (int r = 0; r < 4; ++r)
          fl[(rloc + r) * ST + cloc] = acc[mt][nt][r];
      }
    __syncthreads();
    float* Cc = (float*)Cv;
#pragma unroll
    for (int rp = 0; rp < 64; rp += 16) {
      int row = rp + tid / 16, seg = tid % 16;
      float4 vv = *(const float4*)&fl[row * ST + seg * 4];
      float4 bb = *(const float4*)&bias[n0 + seg * 4];
      vv.x += bb.x; vv.y += bb.y; vv.z += bb.z; vv.w += bb.w;
      *(float4*)&Cc[(size_t)(m0 + row) * N + n0 + seg * 4] = vv;
    }
  }
}

// ---------------------------------------------------------------------------
// MFMA windowed attention (unchanged, verified). Block = 64 rows x 1 head;
// 4 waves, 16-row strips; V b-frags prefetched before the softmax phase.
// ---------------------------------------------------------------------------
__global__ __launch_bounds__(256) void attn_mfma(
    const short* __restrict__ qkvb, const short* __restrict__ vT,
    short* __restrict__ attnb) {
  const int blk = blockIdx.x;
  const int h = blk % HEADS;
  const int l0 = (blk / HEADS) * 64;
  const int sb = l0 - PADW;

  const int tid = threadIdx.x;
  const int wv = tid >> 6, lane = tid & 63;
  const int lanelo = lane & 15, quad = lane >> 4;
  const int qoff = h * 192, koff = h * 192 + 64;

  __shared__ __align__(16) short P_lds[64 * 136];

  // Q a-frags
  const short* qp = qkvb + (size_t)(l0 + wv * 16 + lanelo) * QKV_N + qoff;
  short8 aq0 = *(const short8*)(qp + quad * 8);
  short8 aq1 = *(const short8*)(qp + 32 + quad * 8);

  // ---- S = Q.K^T
  f32x4 sacc[8] = {};
#pragma unroll
  for (int nt = 0; nt < 8; ++nt) {
    int gl = sb + nt * 16 + lanelo;
    short8 bk0 = {}, bk1 = {};
    if ((unsigned)gl < (unsigned)LSEQ) {
      const short* kp = qkvb + (size_t)gl * QKV_N + koff;
      bk0 = *(const short8*)(kp + quad * 8);
      bk1 = *(const short8*)(kp + 32 + quad * 8);
    }
    sacc[nt] = __builtin_amdgcn_mfma_f32_16x16x32_bf16(aq0, bk0, sacc[nt], 0, 0, 0);
    sacc[nt] = __builtin_amdgcn_mfma_f32_16x16x32_bf16(aq1, bk1, sacc[nt], 0, 0, 0);
  }

  // ---- V b-frag prefetch (independent of softmax)
  short8 bv[4][4];
#pragma unroll
  for (int ks = 0; ks < 4; ++ks) {
    int lp = l0 + ks * 32 + quad * 8;
#pragma unroll
    for (int nt = 0; nt < 4; ++nt) {
      int d = nt * 16 + lanelo;
      bv[ks][nt] = *(const short8*)&vT[((size_t)h * 64 + d) * LPAD + lp];
    }
  }

  // ---- softmax per row (no max-pass; masked -> exp(-1e30) == 0)
  float rsum[4] = {0.f, 0.f, 0.f, 0.f};
#pragma unroll
  for (int nt = 0; nt < 8; ++nt)
#pragma unroll
    for (int r = 0; r < 4; ++r) {
      int li = wv * 16 + quad * 4 + r;
      int widx = nt * 16 + lanelo - li;
      float s = (widx >= 0 && widx <= 64) ? sacc[nt][r] * 0.125f : -1e30f;
      float p = __expf(s);
      sacc[nt][r] = p;
      rsum[r] += p;
    }
#pragma unroll
  for (int r = 0; r < 4; ++r) {
#pragma unroll
    for (int off = 1; off < 16; off <<= 1)
      rsum[r] += __shfl_xor(rsum[r], off);
    rsum[r] = 1.f / rsum[r];
  }
#pragma unroll
  for (int nt = 0; nt < 8; ++nt)
#pragma unroll
    for (int r = 0; r < 4; ++r) {
      int row = wv * 16 + quad * 4 + r;
      P_lds[row * 136 + nt * 16 + lanelo] = f2bf(sacc[nt][r] * rsum[r]);
    }
  __syncthreads();

  // ---- O = P.V (V already in regs)
  f32x4 oacc[4] = {};
#pragma unroll
  for (int ks = 0; ks < 4; ++ks) {
    short8 ap = *(const short8*)&P_lds[(wv * 16 + lanelo) * 136 + ks * 32 + quad * 8];
#pragma unroll
    for (int nt = 0; nt < 4; ++nt)
      oacc[nt] = __builtin_amdgcn_mfma_f32_16x16x32_bf16(ap, bv[ks][nt], oacc[nt], 0, 0, 0);
  }

  // ---- coalesced O store through LDS (stride 80 shorts)
  __syncthreads();
#pragma unroll
  for (int nt = 0; nt < 4; ++nt)
#pragma unroll
    for (int r = 0; r < 4; ++r) {
      int row = wv * 16 + quad * 4 + r;
      P_lds[row * 80 + nt * 16 + lanelo] = f2bf(oacc[nt][r]);
    }
  __syncthreads();
#pragma unroll
  for (int rp = 0; rp < 64; rp += 32) {
    int row = rp + tid / 8, seg = tid % 8;
    short8 vv = *(const short8*)&P_lds[row * 80 + seg * 8];
    *(short8*)&attnb[(size_t)(l0 + row) * EMBED + h * 64 + seg * 8] = vv;
  }
}

extern "C" void kernel_launch(void* const* d_in, const int* in_sizes, int n_in,
                              void* d_out, int out_size, void* d_ws, size_t ws_size,
                              hipStream_t stream) {
  const float* x     = (const float*)d_in[0];   // [2048, 768]
  const float* w_qkv = (const float*)d_in[1];   // [768, 2304]
  const float* w_out = (const float*)d_in[2];   // [768, 768]
  const float* b_out = (const float*)d_in[3];   // [768]
  float* out = (float*)d_out;                   // [2048, 768]

  short *xb, *wqkvT, *woutT, *qkvb, *vT, *attnb;
  (void)hipGetSymbolAddress((void**)&xb,    HIP_SYMBOL(g_xb));
  (void)hipGetSymbolAddress((void**)&wqkvT, HIP_SYMBOL(g_wqkvT));
  (void)hipGetSymbolAddress((void**)&woutT, HIP_SYMBOL(g_woutT));
  (void)hipGetSymbolAddress((void**)&qkvb,  HIP_SYMBOL(g_qkvb));
  (void)hipGetSymbolAddress((void**)&vT,    HIP_SYMBOL(g_vT));
  (void)hipGetSymbolAddress((void**)&attnb, HIP_SYMBOL(g_attnb));

  // 1) fused prep (x cast, both weight transposes, vT pad zero)
  prep<<<PREP_TOT, 256, 0, stream>>>(x, w_qkv, w_out, xb, wqkvT, woutT, vT);

  // 2) qkv = x @ w_qkv -> bf16, fused V^T scatter. 1152 blocks (1D,
  //    XCD-swizzled in-kernel).
  gemm_pipe64<true, true><<<(QKV_N / 64) * (LSEQ / 64), 256, 0, stream>>>(
      xb, wqkvT, nullptr, qkvb, vT, LSEQ, QKV_N, EMBED);

  // 3) windowed attention -> attnb (bf16). 384 blocks.
  attn_mfma<<<(LSEQ / 64) * HEADS, 256, 0, stream>>>(qkvb, vT, attnb);

  // 4) out = attn @ w_out + b_out (fp32). 384 blocks (1D, XCD-swizzled).
  gemm_pipe64<false, false><<<(EMBED / 64) * (LSEQ / 64), 256, 0, stream>>>(
      attnb, woutT, b_out, out, nullptr, LSEQ, EMBED, EMBED);
}

// Round 12
// 110.809 us; speedup vs baseline: 1.0207x; 1.0207x over previous
//
#include <hip/hip_runtime.h>
#include <hip/hip_bf16.h>

#define HEADS 12
#define HD 64
#define PADW 32
#define EMBED 768
#define LSEQ 2048
#define QKV_N (3 * HEADS * HD)   // 2304
#define LPAD (LSEQ + 64)         // 2112

typedef short short8 __attribute__((ext_vector_type(8)));
typedef short short4v __attribute__((ext_vector_type(4)));
typedef float f32x4 __attribute__((ext_vector_type(4)));

// Static scratch, fully overwritten every call (poison-safe).
__device__ short g_xb[LSEQ * EMBED];        // x bf16             [2048][768]
__device__ short g_wqkvT[QKV_N * EMBED];    // w_qkv^T bf16       [2304][768]
__device__ short g_woutT[EMBED * EMBED];    // w_out^T bf16       [768][768]
__device__ short g_qkvb[LSEQ * QKV_N];      // qkv bf16           [2048][2304]
__device__ short g_vT[HEADS * HD * LPAD];   // V^T bf16, 0-padded [768][2112]
__device__ short g_attnb[LSEQ * EMBED];     // attn out bf16      [2048][768]

__device__ __forceinline__ short f2bf(float f) {
  unsigned x = __builtin_bit_cast(unsigned, f);
  x += 0x7fffu + ((x >> 16) & 1u);   // RNE
  return (short)(x >> 16);
}

#define GLB(p) ((const __attribute__((address_space(1))) void*)(p))
#define LDS(p) ((__attribute__((address_space(3))) void*)(p))

// ---------------------------------------------------------------------------
// prep (unchanged, verified): A = cast x, B = w_qkv transpose, C = w_out
// transpose, D = zero vT pads. One dispatch, 3864 blocks.
// ---------------------------------------------------------------------------
#define PREP_A 1536              // (2048*768/4)/256
#define PREP_B 1728              // w_qkv: 72 x 24 tiles of 32x32
#define PREP_C 576               // w_out: 24 x 24
#define PREP_D 24                // vT pad zero
#define PREP_TOT (PREP_A + PREP_B + PREP_C + PREP_D)

__global__ __launch_bounds__(256) void prep(
    const float* __restrict__ x, const float* __restrict__ w_qkv,
    const float* __restrict__ w_out, short* __restrict__ xb,
    short* __restrict__ wqkvT, short* __restrict__ woutT,
    short* __restrict__ vT) {
  __shared__ float T[32][33];
  const int b = blockIdx.x, tid = threadIdx.x;
  if (b < PREP_A) {
    int i = b * 256 + tid;
    float4 v = ((const float4*)x)[i];
    short4v o;
    o[0] = f2bf(v.x); o[1] = f2bf(v.y); o[2] = f2bf(v.z); o[3] = f2bf(v.w);
    ((short4v*)xb)[i] = o;
  } else if (b < PREP_A + PREP_B + PREP_C) {
    const float* W; short* WT; int N, bx, by;
    if (b < PREP_A + PREP_B) {
      int t = b - PREP_A; W = w_qkv; WT = wqkvT; N = QKV_N; bx = t % 72; by = t / 72;
    } else {
      int t = b - PREP_A - PREP_B; W = w_out; WT = woutT; N = EMBED; bx = t % 24; by = t / 24;
    }
    const int K = EMBED;
    int tx = tid & 31, ty = tid >> 5;
    int n0 = bx * 32, k0 = by * 32;
#pragma unroll
    for (int p = 0; p < 4; ++p)
      T[ty + p * 8][tx] = W[(size_t)(k0 + ty + p * 8) * N + n0 + tx];
    __syncthreads();
#pragma unroll
    for (int p = 0; p < 4; ++p)
      WT[(size_t)(n0 + ty + p * 8) * K + k0 + tx] = f2bf(T[tx][ty + p * 8]);
  } else {
    int j = (b - PREP_A - PREP_B - PREP_C) * 256 + tid;
    int hd = j >> 3, side = (j >> 2) & 1, off = (j & 3) * 8;
    short8 z = {};
    *(short8*)&vT[(size_t)hd * LPAD + side * 2080 + off] = z;
  }
}

// ---------------------------------------------------------------------------
// ROUND 12: wave-private barrier-free GEMM pipeline.
// Model revision (r9+r11 post-mortems): r9's BK 32->64 win kept total LDS
// reads and staged bytes IDENTICAL — it only halved the count of
// barrier/vmcnt lockstep events (~450cy each). r11's depth-3 + XCD-L2
// attack on load latency was NULL -> loads are already covered at depth 2;
// the per-step cost is inter-wave CONVERGENCE (4 waves drain vmcnt, meet at
// s_barrier, serialize on the LDS pipe; slowest wave paces).
// Fix: each wave owns a private 32x32 output tile + private 2x8KB LDS
// buffers, loads exactly the A/B rows it consumes, and paces itself only
// by its own vmcnt counter. ZERO block-wide barriers in the kernel
// (epilogue bounce is wave-private too). Geometry, MFMA order, and swizzled
// chunk scheme identical to r9 -> bit-identical results.
// WAR without barriers: ds_reads of buf j drained by lgkmcnt(0) BEFORE
// stage(j+2) is issued into the same buffer (single-wave program order,
// "memory"-fenced asm). vmcnt ledger: 8 loads/stage; steady wait vmcnt(8)
// retires stage j; final iter waits vmcnt(0).
// Cost accepted: 2x staging traffic (no inter-wave sharing) — we run at
// ~12% HBM, absorbed by L2/parallelism.
// ---------------------------------------------------------------------------
template <bool OUT_BF16, bool FUSE_VT>
__global__ __launch_bounds__(256) void gemm_wp64(
    const short* __restrict__ A, const short* __restrict__ Bt,
    const float* __restrict__ bias, void* __restrict__ Cv,
    short* __restrict__ vT, int M, int N, int K) {
  // 4 waves x 2 buffers x (A 32x64 + B 32x64) shorts = 65536 B total.
  __shared__ __align__(16) short lds_s[4 * 2 * 4096];

  const int tid = threadIdx.x;
  const int wv = tid >> 6, lane = tid & 63;
  const int wm = wv >> 1, wn = wv & 1;
  const int lanelo = lane & 15, quad = lane >> 4;
  const int m0 = blockIdx.y * 64 + wm * 32;      // wave-owned 32 rows
  const int n0 = blockIdx.x * 64 + wn * 32;      // wave-owned 32 cols
  const int srow8 = lane >> 3, schk = lane & 7;  // 8 rows x 8 16B chunks
  const int sgc = schk ^ srow8;                  // swizzled global chunk
  const int xk = lanelo & 7;                     // read-side XOR key
  short* wlds = lds_s + wv * 2 * 4096;           // wave-private 16KB

  f32x4 acc[2][2] = {};

  auto stage = [&](int j, int buf) {
    short* Ab = wlds + buf * 4096;               // A: 2048 shorts
    short* Bb = Ab + 2048;                       // B: 2048 shorts
    const int k0 = j * 64;
#pragma unroll
    for (int c = 0; c < 4; ++c) {                // 8 rows per pass
      int row = c * 8 + srow8;
      const short* ga = A + (size_t)(m0 + row) * K + k0 + sgc * 8;
      __builtin_amdgcn_global_load_lds(GLB(ga), LDS(&Ab[c * 8 * 64]), 16, 0, 0);
    }
#pragma unroll
    for (int c = 0; c < 4; ++c) {
      int row = c * 8 + srow8;
      const short* gb = Bt + (size_t)(n0 + row) * K + k0 + sgc * 8;
      __builtin_amdgcn_global_load_lds(GLB(gb), LDS(&Bb[c * 8 * 64]), 16, 0, 0);
    }
  };

  const int steps = K / 64;                      // 12
  stage(0, 0);
  stage(1, 1);
  for (int j = 0; j < steps; ++j) {
    const int buf = j & 1;
    if (j < steps - 1) asm volatile("s_waitcnt vmcnt(8)" ::: "memory");
    else               asm volatile("s_waitcnt vmcnt(0)" ::: "memory");
    short* Ab = wlds + buf * 4096;
    short* Bb = Ab + 2048;
    short8 af[2][2], bfr[2][2];                  // [ks][mt/nt]
#pragma unroll
    for (int ks = 0; ks < 2; ++ks) {
      int p = (ks * 4 + quad) ^ xk;              // physical chunk
#pragma unroll
      for (int mt = 0; mt < 2; ++mt)
        af[ks][mt] = *(const short8*)&Ab[(mt * 16 + lanelo) * 64 + p * 8];
#pragma unroll
      for (int nt = 0; nt < 2; ++nt)
        bfr[ks][nt] = *(const short8*)&Bb[(nt * 16 + lanelo) * 64 + p * 8];
    }
    asm volatile("s_waitcnt lgkmcnt(0)" ::: "memory");   // frags in regs
    if (j + 2 < steps) stage(j + 2, buf);        // overwrite now-drained buf
#pragma unroll
    for (int ks = 0; ks < 2; ++ks)
#pragma unroll
      for (int mt = 0; mt < 2; ++mt)
#pragma unroll
        for (int nt = 0; nt < 2; ++nt)
          acc[mt][nt] = __builtin_amdgcn_mfma_f32_16x16x32_bf16(
              af[ks][mt], bfr[ks][nt], acc[mt][nt], 0, 0, 0);
  }

  // ---- fused V^T scatter: any 16-col group with c0 % 192 >= 128 is V ----
  if (FUSE_VT) {
#pragma unroll
    for (int nt = 0; nt < 2; ++nt) {
      int c0 = n0 + nt * 16;                     // wave-uniform
      if ((c0 % 192) >= 128) {
        int h = c0 / 192, d0 = (c0 % 192) - 128;
#pragma unroll
        for (int mt = 0; mt < 2; ++mt) {
          int d = d0 + lanelo;
          int row0 = m0 + mt * 16 + quad * 4;
          short4v o;
#pragma unroll
          for (int r = 0; r < 4; ++r) o[r] = f2bf(acc[mt][nt][r]);
          *(short4v*)&vT[(size_t)(h * 64 + d) * LPAD + PADW + row0] = o;
        }
      }
    }
  }

  // ---- wave-private coalesced epilogue (no __syncthreads anywhere) ----
  if (OUT_BF16) {
    constexpr int ST = 40;                       // 32 + 8 pad shorts
    short* eb = wlds;                            // K-loop buffers dead
#pragma unroll
    for (int mt = 0; mt < 2; ++mt)
#pragma unroll
      for (int nt = 0; nt < 2; ++nt) {
        int rloc = mt * 16 + quad * 4;
        int cloc = nt * 16 + lanelo;
#pragma unroll
        for (int r = 0; r < 4; ++r)
          eb[(rloc + r) * ST + cloc] = f2bf(acc[mt][nt][r]);
      }
    asm volatile("s_waitcnt lgkmcnt(0)" ::: "memory");
    short* Cc = (short*)Cv;
#pragma unroll
    for (int pass = 0; pass < 2; ++pass) {
      int u = pass * 64 + lane;
      int row = u >> 2, seg = u & 3;             // 32 rows x 4 x short8
      short8 vv = *(const short8*)&eb[row * ST + seg * 8];
      *(short8*)&Cc[(size_t)(m0 + row) * N + n0 + seg * 8] = vv;
    }
  } else {
    constexpr int ST = 36;                       // 32 + 4 pad floats
    float* fl = (float*)wlds;
#pragma unroll
    for (int mt = 0; mt < 2; ++mt)
#pragma unroll
      for (int nt = 0; nt < 2; ++nt) {
        int rloc = mt * 16 + quad * 4;
        int cloc = nt * 16 + lanelo;
#pragma unroll
        for (int r = 0; r < 4; ++r)
          fl[(rloc + r) * ST + cloc] = acc[mt][nt][r];
      }
    asm volatile("s_waitcnt lgkmcnt(0)" ::: "memory");
    float* Cc = (float*)Cv;
#pragma unroll
    for (int pass = 0; pass < 4; ++pass) {
      int u = pass * 64 + lane;
      int row = u >> 3, seg = u & 7;             // 32 rows x 8 x float4
      float4 vv = *(const float4*)&fl[row * ST + seg * 4];
      float4 bb = *(const float4*)&bias[n0 + seg * 4];
      vv.x += bb.x; vv.y += bb.y; vv.z += bb.z; vv.w += bb.w;
      *(float4*)&Cc[(size_t)(m0 + row) * N + n0 + seg * 4] = vv;
    }
  }
}

// ---------------------------------------------------------------------------
// MFMA windowed attention (unchanged, verified). Block = 64 rows x 1 head;
// 4 waves, 16-row strips; V b-frags prefetched before the softmax phase.
// ---------------------------------------------------------------------------
__global__ __launch_bounds__(256) void attn_mfma(
    const short* __restrict__ qkvb, const short* __restrict__ vT,
    short* __restrict__ attnb) {
  const int blk = blockIdx.x;
  const int h = blk % HEADS;
  const int l0 = (blk / HEADS) * 64;
  const int sb = l0 - PADW;

  const int tid = threadIdx.x;
  const int wv = tid >> 6, lane = tid & 63;
  const int lanelo = lane & 15, quad = lane >> 4;
  const int qoff = h * 192, koff = h * 192 + 64;

  __shared__ __align__(16) short P_lds[64 * 136];

  // Q a-frags
  const short* qp = qkvb + (size_t)(l0 + wv * 16 + lanelo) * QKV_N + qoff;
  short8 aq0 = *(const short8*)(qp + quad * 8);
  short8 aq1 = *(const short8*)(qp + 32 + quad * 8);

  // ---- S = Q.K^T
  f32x4 sacc[8] = {};
#pragma unroll
  for (int nt = 0; nt < 8; ++nt) {
    int gl = sb + nt * 16 + lanelo;
    short8 bk0 = {}, bk1 = {};
    if ((unsigned)gl < (unsigned)LSEQ) {
      const short* kp = qkvb + (size_t)gl * QKV_N + koff;
      bk0 = *(const short8*)(kp + quad * 8);
      bk1 = *(const short8*)(kp + 32 + quad * 8);
    }
    sacc[nt] = __builtin_amdgcn_mfma_f32_16x16x32_bf16(aq0, bk0, sacc[nt], 0, 0, 0);
    sacc[nt] = __builtin_amdgcn_mfma_f32_16x16x32_bf16(aq1, bk1, sacc[nt], 0, 0, 0);
  }

  // ---- V b-frag prefetch (independent of softmax)
  short8 bv[4][4];
#pragma unroll
  for (int ks = 0; ks < 4; ++ks) {
    int lp = l0 + ks * 32 + quad * 8;
#pragma unroll
    for (int nt = 0; nt < 4; ++nt) {
      int d = nt * 16 + lanelo;
      bv[ks][nt] = *(const short8*)&vT[((size_t)h * 64 + d) * LPAD + lp];
    }
  }

  // ---- softmax per row (no max-pass; masked -> exp(-1e30) == 0)
  float rsum[4] = {0.f, 0.f, 0.f, 0.f};
#pragma unroll
  for (int nt = 0; nt < 8; ++nt)
#pragma unroll
    for (int r = 0; r < 4; ++r) {
      int li = wv * 16 + quad * 4 + r;
      int widx = nt * 16 + lanelo - li;
      float s = (widx >= 0 && widx <= 64) ? sacc[nt][r] * 0.125f : -1e30f;
      float p = __expf(s);
      sacc[nt][r] = p;
      rsum[r] += p;
    }
#pragma unroll
  for (int r = 0; r < 4; ++r) {
#pragma unroll
    for (int off = 1; off < 16; off <<= 1)
      rsum[r] += __shfl_xor(rsum[r], off);
    rsum[r] = 1.f / rsum[r];
  }
#pragma unroll
  for (int nt = 0; nt < 8; ++nt)
#pragma unroll
    for (int r = 0; r < 4; ++r) {
      int row = wv * 16 + quad * 4 + r;
      P_lds[row * 136 + nt * 16 + lanelo] = f2bf(sacc[nt][r] * rsum[r]);
    }
  __syncthreads();

  // ---- O = P.V (V already in regs)
  f32x4 oacc[4] = {};
#pragma unroll
  for (int ks = 0; ks < 4; ++ks) {
    short8 ap = *(const short8*)&P_lds[(wv * 16 + lanelo) * 136 + ks * 32 + quad * 8];
#pragma unroll
    for (int nt = 0; nt < 4; ++nt)
      oacc[nt] = __builtin_amdgcn_mfma_f32_16x16x32_bf16(ap, bv[ks][nt], oacc[nt], 0, 0, 0);
  }

  // ---- coalesced O store through LDS (stride 80 shorts)
  __syncthreads();
#pragma unroll
  for (int nt = 0; nt < 4; ++nt)
#pragma unroll
    for (int r = 0; r < 4; ++r) {
      int row = wv * 16 + quad * 4 + r;
      P_lds[row * 80 + nt * 16 + lanelo] = f2bf(oacc[nt][r]);
    }
  __syncthreads();
#pragma unroll
  for (int rp = 0; rp < 64; rp += 32) {
    int row = rp + tid / 8, seg = tid % 8;
    short8 vv = *(const short8*)&P_lds[row * 80 + seg * 8];
    *(short8*)&attnb[(size_t)(l0 + row) * EMBED + h * 64 + seg * 8] = vv;
  }
}

extern "C" void kernel_launch(void* const* d_in, const int* in_sizes, int n_in,
                              void* d_out, int out_size, void* d_ws, size_t ws_size,
                              hipStream_t stream) {
  const float* x     = (const float*)d_in[0];   // [2048, 768]
  const float* w_qkv = (const float*)d_in[1];   // [768, 2304]
  const float* w_out = (const float*)d_in[2];   // [768, 768]
  const float* b_out = (const float*)d_in[3];   // [768]
  float* out = (float*)d_out;                   // [2048, 768]

  short *xb, *wqkvT, *woutT, *qkvb, *vT, *attnb;
  (void)hipGetSymbolAddress((void**)&xb,    HIP_SYMBOL(g_xb));
  (void)hipGetSymbolAddress((void**)&wqkvT, HIP_SYMBOL(g_wqkvT));
  (void)hipGetSymbolAddress((void**)&woutT, HIP_SYMBOL(g_woutT));
  (void)hipGetSymbolAddress((void**)&qkvb,  HIP_SYMBOL(g_qkvb));
  (void)hipGetSymbolAddress((void**)&vT,    HIP_SYMBOL(g_vT));
  (void)hipGetSymbolAddress((void**)&attnb, HIP_SYMBOL(g_attnb));

  // 1) fused prep (x cast, both weight transposes, vT pad zero)
  prep<<<PREP_TOT, 256, 0, stream>>>(x, w_qkv, w_out, xb, wqkvT, woutT, vT);

  // 2) qkv = x @ w_qkv -> bf16, fused V^T scatter. 1152 blocks, barrier-free.
  gemm_wp64<true, true><<<dim3(QKV_N / 64, LSEQ / 64), 256, 0, stream>>>(
      xb, wqkvT, nullptr, qkvb, vT, LSEQ, QKV_N, EMBED);

  // 3) windowed attention -> attnb (bf16). 384 blocks.
  attn_mfma<<<(LSEQ / 64) * HEADS, 256, 0, stream>>>(qkvb, vT, attnb);

  // 4) out = attn @ w_out + b_out (fp32). 384 blocks, barrier-free.
  gemm_wp64<false, false><<<dim3(EMBED / 64, LSEQ / 64), 256, 0, stream>>>(
      attnb, woutT, b_out, out, nullptr, LSEQ, EMBED, EMBED);
}